// Round 17
// baseline (122.076 us; speedup 1.0000x reference)
//
#include <hip/hip_runtime.h>
#include <stdint.h>

// ---------- types & helpers ----------
typedef __attribute__((ext_vector_type(4)))  float    f32x4;
typedef f32x4 __attribute__((aligned(4)))    f32x4u;  // 4B-aligned vector load (global allows it)
typedef __attribute__((ext_vector_type(16))) float    f32x16;
typedef __attribute__((ext_vector_type(8)))  short    bf16x8;  // 8 bf16 (4 VGPRs) — MFMA operand
typedef __attribute__((ext_vector_type(2)))  uint32_t u32x2;
typedef __attribute__((ext_vector_type(4)))  uint32_t u32x4;

#define MFMA16(a,b,c) __builtin_amdgcn_mfma_f32_16x16x32_bf16((a),(b),(c),0,0,0)
#define MFMA32(a,b,c) __builtin_amdgcn_mfma_f32_32x32x16_bf16((a),(b),(c),0,0,0)

__device__ __forceinline__ uint16_t f2bf(float f){
  uint32_t u = __float_as_uint(f);
  return (uint16_t)((u + 0x7FFFu + ((u >> 16) & 1u)) >> 16);   // RNE
}

// packed f32x2 -> bf16x2 (RNE), single instruction
__device__ __forceinline__ uint32_t pk_bf16(float lo, float hi){
  uint32_t r; asm("v_cvt_pk_bf16_f32 %0, %1, %2" : "=v"(r) : "v"(lo), "v"(hi)); return r;
}

__device__ __forceinline__ float fast_exp2(float x){
  float r; asm("v_exp_f32 %0, %1" : "=v"(r) : "v"(x)); return r;
}

// async global->LDS, 16B per lane; LDS dest must be (wave-uniform base + lane*16)
__device__ __forceinline__ void gload16(const uint16_t* g, uint16_t* l){
  __builtin_amdgcn_global_load_lds((const __attribute__((address_space(1))) uint32_t*)g,
                                   (__attribute__((address_space(3))) uint32_t*)l, 16, 0, 0);
}

typedef union { u32x4 u; bf16x8 b; } pun_t;

// ---------- fused prep (single launch, 5376 blocks) ----------
__global__ void k_prep(const float* __restrict__ x, uint16_t* __restrict__ x_bf,
                       const float* __restrict__ btab, float* __restrict__ bias_t,
                       const float* __restrict__ qkv_w, uint16_t* __restrict__ qkv_wt,
                       const float* __restrict__ proj_w, uint16_t* __restrict__ proj_wt){
  __shared__ float tile[64][65];
  const int bx = blockIdx.x;
  if (bx < 4096){
    const size_t i = (size_t)(bx*256 + threadIdx.x) * 4;
    const f32x4 v = *(const f32x4*)(x + i);
    u32x2 pk = {pk_bf16(v[0], v[1]), pk_bf16(v[2], v[3])};
    *(u32x2*)(x_bf + i) = pk;
    return;
  }
  if (bx < 4352){
    const int i = (bx - 4096)*256 + threadIdx.x;
    if (i < 4095*16) bias_t[(i & 15)*4096 + (i >> 4)] = btab[i] * 1.4426950408889634f;
    return;
  }
  const float* in;  uint16_t* out;  int K, N, n0, k0;
  if (bx < 5120){
    const int b2 = bx - 4352;
    in = qkv_w; out = qkv_wt; K = 1024; N = 3072;
    n0 = (b2 % 48)*64; k0 = (b2 / 48)*64;
  } else {
    const int b3 = bx - 5120;
    in = proj_w; out = proj_wt; K = 1024; N = 1024;
    n0 = (b3 % 16)*64; k0 = (b3 / 16)*64;
  }
  const int tc = threadIdx.x & 63, tr = threadIdx.x >> 6;
  #pragma unroll
  for (int p=0;p<16;p++){ int r = p*4 + tr; tile[r][tc] = in[(size_t)(k0+r)*N + n0 + tc]; }
  __syncthreads();
  #pragma unroll
  for (int p=0;p<16;p++){ int r = p*4 + tr; out[(size_t)(n0+r)*K + k0 + tc] = f2bf(tile[tc][r]); }
}

// ---------- GEMM0: C(4096 x 3072) = A * Bt^T, BM=64, BN=128, BK=64; q/k/v scatter ----------
__global__ __launch_bounds__(256, 2) void k_gemm(
    const uint16_t* __restrict__ A, const uint16_t* __restrict__ Bt,
    const float* __restrict__ bias,
    uint16_t* __restrict__ qo, uint16_t* __restrict__ ko, uint16_t* __restrict__ vto)
{
  __shared__ __align__(16) uint16_t at[64*64];
  __shared__ __align__(16) uint16_t bt[128*64];
  const int tid = threadIdx.x;
  const int lane = tid & 63, wc = tid >> 6;
  const int g = lane >> 4, li = lane & 15;
  const int m0 = blockIdx.y * 64, n0 = blockIdx.x * 128;

  f32x4 acc[4][2] = {};

  const int srow = tid >> 3;
  const int scg  = (tid & 7) ^ (srow & 7);

  for (int kt_ = 0; kt_ < 16; kt_++){
    const int kk = kt_*64;
    __syncthreads();
    #pragma unroll
    for (int j = 0; j < 2; j++)
      gload16(A  + (size_t)(m0 + j*32 + srow)*1024 + kk + scg*8, at + (j*256+tid)*8);
    #pragma unroll
    for (int j = 0; j < 4; j++)
      gload16(Bt + (size_t)(n0 + j*32 + srow)*1024 + kk + scg*8, bt + (j*256+tid)*8);
    asm volatile("s_waitcnt vmcnt(0)" ::: "memory");
    __syncthreads();

    bf16x8 af[2][4], bfr[2][2];
    #pragma unroll
    for (int mi=0; mi<4; mi++){
      int row = mi*16 + li, sw = row & 7;
      af[0][mi] = *(const bf16x8*)(at + row*64 + ((g     ^ sw)*8));
      af[1][mi] = *(const bf16x8*)(at + row*64 + (((4+g) ^ sw)*8));
    }
    #pragma unroll
    for (int ni=0; ni<2; ni++){
      int row = wc*32 + ni*16 + li, sw = row & 7;
      bfr[0][ni] = *(const bf16x8*)(bt + row*64 + ((g     ^ sw)*8));
      bfr[1][ni] = *(const bf16x8*)(bt + row*64 + (((4+g) ^ sw)*8));
    }
    #pragma unroll
    for (int s=0; s<2; s++)
      #pragma unroll
      for (int mi=0; mi<4; mi++)
        #pragma unroll
        for (int ni=0; ni<2; ni++)
          acc[mi][ni] = MFMA16(af[s][mi], bfr[s][ni], acc[mi][ni]);
  }

  #pragma unroll
  for (int ni=0; ni<2; ni++){
    const int c = n0 + wc*32 + ni*16 + li;
    const float bv = bias[c];
    const int which = c >> 10, cc = c & 1023;
    const int h = cc >> 6, d = cc & 63;
    #pragma unroll
    for (int mi=0; mi<4; mi++){
      const int trow = m0 + mi*16 + g*4;
      const int b_ = trow >> 11, lcl = trow & 2047;
      const f32x4 v4 = acc[mi][ni];
      if (which == 0){
        uint16_t* dst = qo + (((size_t)(b_*16 + h)*2048 + lcl)*64 + d);
        #pragma unroll
        for (int r=0;r<4;r++) dst[(size_t)r*64] = f2bf((v4[r] + bv) * 0.18033688011112042f);
      } else if (which == 1){
        uint16_t* dst = ko + (((size_t)(b_*16 + h)*2048 + lcl)*64 + d);
        #pragma unroll
        for (int r=0;r<4;r++) dst[(size_t)r*64] = f2bf(v4[r] + bv);
      } else {
        u32x2 pk = {pk_bf16(v4[0]+bv, v4[1]+bv), pk_bf16(v4[2]+bv, v4[3]+bv)};
        *(u32x2*)(vto + (((size_t)(b_*16 + h)*64 + d)*2048 + lcl)) = pk;
      }
    }
  }
}

// ---------- GEMM1 (proj): C(4096 x 1024) = A * Bt^T, BM=128, BN=64 -> 512 blocks ----------
__global__ __launch_bounds__(256, 2) void k_gemm2(
    const uint16_t* __restrict__ A, const uint16_t* __restrict__ Bt,
    const float* __restrict__ bias, float* __restrict__ outf)
{
  __shared__ __align__(16) uint16_t at[128*64];
  __shared__ __align__(16) uint16_t bt[64*64];
  const int tid = threadIdx.x;
  const int lane = tid & 63, w = tid >> 6;
  const int g = lane >> 4, li = lane & 15;
  const int wr = w >> 1, wc = w & 1;
  const int m0 = blockIdx.y * 128, n0 = blockIdx.x * 64;

  f32x4 acc[4][2] = {};
  const int srow = tid >> 3;
  const int scg  = (tid & 7) ^ (srow & 7);

  for (int kt_ = 0; kt_ < 16; kt_++){
    const int kk = kt_*64;
    __syncthreads();
    #pragma unroll
    for (int j = 0; j < 4; j++)
      gload16(A  + (size_t)(m0 + j*32 + srow)*1024 + kk + scg*8, at + (j*256+tid)*8);
    #pragma unroll
    for (int j = 0; j < 2; j++)
      gload16(Bt + (size_t)(n0 + j*32 + srow)*1024 + kk + scg*8, bt + (j*256+tid)*8);
    asm volatile("s_waitcnt vmcnt(0)" ::: "memory");
    __syncthreads();

    bf16x8 af[2][4], bfr[2][2];
    #pragma unroll
    for (int mi=0; mi<4; mi++){
      int row = wr*64 + mi*16 + li, sw = row & 7;
      af[0][mi] = *(const bf16x8*)(at + row*64 + ((g     ^ sw)*8));
      af[1][mi] = *(const bf16x8*)(at + row*64 + (((4+g) ^ sw)*8));
    }
    #pragma unroll
    for (int ni=0; ni<2; ni++){
      int row = wc*32 + ni*16 + li, sw = row & 7;
      bfr[0][ni] = *(const bf16x8*)(bt + row*64 + ((g     ^ sw)*8));
      bfr[1][ni] = *(const bf16x8*)(bt + row*64 + (((4+g) ^ sw)*8));
    }
    #pragma unroll
    for (int s=0; s<2; s++)
      #pragma unroll
      for (int mi=0; mi<4; mi++)
        #pragma unroll
        for (int ni=0; ni<2; ni++)
          acc[mi][ni] = MFMA16(af[s][mi], bfr[s][ni], acc[mi][ni]);
  }

  #pragma unroll
  for (int ni=0; ni<2; ni++){
    const int c = n0 + wc*32 + ni*16 + li;
    const float bv = bias[c];
    #pragma unroll
    for (int mi=0; mi<4; mi++){
      const int trow = m0 + wr*64 + mi*16 + g*4;
      float* dst = outf + (size_t)trow*1024 + c;
      const f32x4 v4 = acc[mi][ni];
      #pragma unroll
      for (int r=0;r<4;r++) dst[(size_t)r*1024] = v4[r] + bv;
    }
  }
}

// ---------- flash attention: 32x32 MFMA, pair-lane softmax ----------
// 4 waves x 32 q (QBLK=128), KVBLK=64. S^T via mfma_32x32x16 (C/D: col=lane&31,
// row=(reg&3)+8*(reg>>2)+4*(lane>>5)). A lane owns the 4h-offset HALF of its q's kv
// values; partner lane (lane^32) owns the other half -> softmax max is pair-reduced
// with ONE shfl_xor(32)/tile (r16 bug: per-lane max made partner halves use different
// m -> garbage). lrun keeps per-lane half-sums (rescales are pair-uniform) and is
// pair-summed once in the epilogue. P->PV B-frags via 16 cvt_pk + 8 shfl_xor(32);
// P LDS slab gone (LDS 40->32KB). K/V staging + XOR swizzle unchanged.
// NOTE: launch_bounds stays (256,2) — (256,4) spills catastrophically (r8).
__device__ __forceinline__ void attn_tile(
    int t, bool last, int tid, int l31, int h, int srow, int scg,
    const uint16_t* kbase, const uint16_t* vbase, const float* bbl,
    const uint16_t* ktc, uint16_t* ktn, const uint16_t* vtc, uint16_t* vtn,
    const bf16x8 (&qf)[4],
    f32x16& o0, f32x16& o1, float& mrun, float& lrun)
{
  const int kv0 = t*64;

  // bias: 8 f32x4 (lane base bbl already folds head, +2047, -q, +4h)
  f32x4 bv0[4], bv1[4];
  #pragma unroll
  for (int q2=0;q2<4;q2++){
    bv0[q2] = *(const f32x4u*)(bbl + kv0 + 8*q2);
    bv1[q2] = *(const f32x4u*)(bbl + kv0 + 32 + 8*q2);
  }
  asm volatile("" ::: "memory");                           // pin issue order: bias -> staging

  if (!last){
    const int kv1 = kv0 + 64;
    gload16(kbase + (size_t)(kv1+srow)*64 + scg*8,         ktn + tid*8);
    gload16(kbase + (size_t)(kv1+srow+32)*64 + scg*8,      ktn + 2048 + tid*8);
    gload16(vbase + (size_t)srow*2048 + kv1 + scg*8,       vtn + tid*8);
    gload16(vbase + (size_t)(srow+32)*2048 + kv1 + scg*8,  vtn + 2048 + tid*8);
    // queue (old->new): stage(t)4, bias(t)8, stage(t+1)4 = 16 outstanding
    asm volatile("s_waitcnt vmcnt(12)" ::: "memory");      // retire stage(t)
  } else {
    asm volatile("s_waitcnt vmcnt(8)" ::: "memory");       // retire stage(t); keep bias(t)
  }
  __builtin_amdgcn_s_barrier();                            // A: tile t ready

  // S^T(64kv x 32q) = K * Q^T : 2 kv-tiles x 4 K=16 steps
  const int sw = l31 & 7;                                  // rows l31 and 32+l31 share &7
  f32x16 sA = {}, sB = {};
  __builtin_amdgcn_s_setprio(1);
  #pragma unroll
  for (int s=0;s<4;s++){
    const int ch = (((2*s+h) ^ sw))*8;
    bf16x8 a0 = *(const bf16x8*)(ktc + l31*64 + ch);
    bf16x8 a1 = *(const bf16x8*)(ktc + (32+l31)*64 + ch);
    sA = MFMA32(a0, qf[s], sA);
    sB = MFMA32(a1, qf[s], sB);
  }
  __builtin_amdgcn_s_setprio(0);

  // bias add + lane-half max (lane q = col; kv = (r&3)+8*(r>>2)+4h + 32*T)
  float tmax = -__builtin_inff();
  #pragma unroll
  for (int r=0;r<16;r++){
    sA[r] += bv0[r>>2][r&3];
    sB[r] += bv1[r>>2][r&3];
    tmax = fmaxf(tmax, fmaxf(sA[r], sB[r]));
  }
  // pair-reduce: partner lane (lane^32) owns the other half of this q's kv values.
  tmax = fmaxf(tmax, __shfl_xor(tmax, 32));

  // defer-max (T13); rescale factors pair-uniform (mrun is)
  const int ok = (tmax <= mrun + 8.f);
  if (!__all(ok)){
    const float mn = fmaxf(mrun, tmax);
    const float al = fast_exp2(mrun - mn);
    #pragma unroll
    for (int r=0;r<16;r++){ o0[r] *= al; o1[r] *= al; }
    lrun *= al; mrun = mn;
  }

  // P = exp2(S-m), per-lane half psum (pair-summed in epilogue), pack to bf16 pairs
  float psum = 0.f;
  uint32_t pkA[8], pkB[8];
  #pragma unroll
  for (int m=0;m<4;m++){
    float a0 = fast_exp2(sA[4*m+0]-mrun), a1 = fast_exp2(sA[4*m+1]-mrun);
    float a2 = fast_exp2(sA[4*m+2]-mrun), a3 = fast_exp2(sA[4*m+3]-mrun);
    float b0 = fast_exp2(sB[4*m+0]-mrun), b1 = fast_exp2(sB[4*m+1]-mrun);
    float b2 = fast_exp2(sB[4*m+2]-mrun), b3 = fast_exp2(sB[4*m+3]-mrun);
    psum += ((a0+a1)+(a2+a3)) + ((b0+b1)+(b2+b3));
    pkA[2*m] = pk_bf16(a0,a1); pkA[2*m+1] = pk_bf16(a2,a3);
    pkB[2*m] = pk_bf16(b0,b1); pkB[2*m+1] = pk_bf16(b2,b3);
  }
  lrun += psum;

  // PV: O^T(64d x 32q) += V^T * P^T ; B-frag per step s: u32{0,1} from h'=0 source,
  // u32{2,3} from h'=1 source, pack index m = 2*(s&1)+h_target -> one shfl_xor(32) pair.
  __builtin_amdgcn_s_setprio(1);
  #pragma unroll
  for (int s=0;s<4;s++){
    const uint32_t* pks = (s < 2) ? pkA : pkB;             // compile-time select
    const int sl = s & 1;
    const uint32_t c0 = pks[4*sl], c1 = pks[4*sl+1], c2 = pks[4*sl+2], c3 = pks[4*sl+3];
    const uint32_t v0 = h ? c0 : c2, v1 = h ? c1 : c3;     // send what partner needs
    const uint32_t r0 = (uint32_t)__shfl_xor((int)v0, 32);
    const uint32_t r1 = (uint32_t)__shfl_xor((int)v1, 32);
    pun_t pn;
    pn.u = (u32x4){ h ? r0 : c0, h ? r1 : c1, h ? c2 : r0, h ? c3 : r1 };
    const int ch = (((2*s+h) ^ sw))*8;
    bf16x8 av0 = *(const bf16x8*)(vtc + l31*64 + ch);
    bf16x8 av1 = *(const bf16x8*)(vtc + (32+l31)*64 + ch);
    o0 = MFMA32(av0, pn.b, o0);
    o1 = MFMA32(av1, pn.b, o1);
  }
  __builtin_amdgcn_s_setprio(0);
  __builtin_amdgcn_s_barrier();                            // B: done reading tile t
}

__global__ __launch_bounds__(256, 2) void k_attn(
    const uint16_t* __restrict__ qg, const uint16_t* __restrict__ kg,
    const uint16_t* __restrict__ vg, const float* __restrict__ biast,
    uint16_t* __restrict__ outp)
{
  __shared__ __align__(16) uint16_t kt[2][64*64];  // K tile [kv][d], 16B-chunk ^= row&7 (16KB)
  __shared__ __align__(16) uint16_t vt[2][64*64];  // V^T tile [d][kv], same swizzle   (16KB)
  const int tid = threadIdx.x;
  const int lane = tid & 63, w = tid >> 6;         // 4 waves
  const int l31 = lane & 31, h = lane >> 5;
  const int bh = blockIdx.y, h_head = bh & 15, b_ = bh >> 4;
  const int qw = blockIdx.x*128 + w*32;
  const int q_tok = qw + l31;                      // lane's q row

  // Q fragments: B-operand, col q = lane&31, k(d) = 16s + 8h + i
  bf16x8 qf[4];
  {
    const uint16_t* qp = qg + ((size_t)bh*2048 + q_tok)*64 + h*8;
    #pragma unroll
    for (int s=0;s<4;s++) qf[s] = *(const bf16x8*)(qp + s*16);
  }

  f32x16 o0 = {}, o1 = {};
  float mrun = -__builtin_inff(), lrun = 0.f;

  const uint16_t* kbase = kg + (size_t)bh*(2048*64);
  const uint16_t* vbase = vg + (size_t)bh*(64*2048);
  const int srow = tid >> 3;
  const int scg  = (tid & 7) ^ (srow & 7);
  const float* bbl = biast + h_head*4096 + 2047 - q_tok + 4*h;  // + kv_glob + {32T,8q2}

  // prologue: stage tile 0
  gload16(kbase + (size_t)srow*64 + scg*8,         &kt[0][tid*8]);
  gload16(kbase + (size_t)(srow+32)*64 + scg*8,    &kt[0][2048 + tid*8]);
  gload16(vbase + (size_t)srow*2048 + scg*8,       &vt[0][tid*8]);
  gload16(vbase + (size_t)(srow+32)*2048 + scg*8,  &vt[0][2048 + tid*8]);

  for (int tt = 0; tt < 32; tt += 2){
    attn_tile(tt,   false,    tid, l31, h, srow, scg, kbase, vbase, bbl,
              &kt[0][0], &kt[1][0], &vt[0][0], &vt[1][0], qf, o0, o1, mrun, lrun);
    attn_tile(tt+1, tt == 30, tid, l31, h, srow, scg, kbase, vbase, bbl,
              &kt[1][0], &kt[0][0], &vt[1][0], &vt[0][0], qf, o0, o1, mrun, lrun);
  }

  // epilogue: pair-sum l (halves scaled identically), in-lane normalize.
  // O^T row d = (r&3)+8*(r>>2)+4h+32T, col q = lane.
  const float ls = lrun + __shfl_xor(lrun, 32);
  const float inv = 1.0f / ls;
  const size_t token = (size_t)b_*2048 + q_tok;
  uint16_t* dst = outp + token*1024 + h_head*64 + 4*h;
  #pragma unroll
  for (int q2=0;q2<4;q2++){
    u32x2 w0 = {pk_bf16(o0[4*q2]*inv, o0[4*q2+1]*inv), pk_bf16(o0[4*q2+2]*inv, o0[4*q2+3]*inv)};
    *(u32x2*)(dst + 8*q2) = w0;
    u32x2 w1 = {pk_bf16(o1[4*q2]*inv, o1[4*q2+1]*inv), pk_bf16(o1[4*q2+2]*inv, o1[4*q2+3]*inv)};
    *(u32x2*)(dst + 32 + 8*q2) = w1;
  }
}

// ---------- launch ----------
extern "C" void kernel_launch(void* const* d_in, const int* in_sizes, int n_in,
                              void* d_out, int out_size, void* d_ws, size_t ws_size,
                              hipStream_t stream)
{
  const float* x      = (const float*)d_in[0];
  const float* qkv_w  = (const float*)d_in[1];
  const float* qkv_b  = (const float*)d_in[2];
  const float* proj_w = (const float*)d_in[3];
  const float* proj_b = (const float*)d_in[4];
  const float* btab   = (const float*)d_in[5];
  float* out = (float*)d_out;

  char* p = (char*)d_ws;
  uint16_t* x_bf    = (uint16_t*)(p);
  uint16_t* qkv_wt  = (uint16_t*)(p + 8388608);
  uint16_t* proj_wt = (uint16_t*)(p + 14680064);
  uint16_t* q_buf   = (uint16_t*)(p + 16777216);   // (b,h,l,d) bf16, prescaled
  uint16_t* k_buf   = (uint16_t*)(p + 25165824);   // (b,h,l,d) bf16
  uint16_t* vt_buf  = (uint16_t*)(p + 33554432);   // (b,h,d,l) bf16
  uint16_t* ao_buf  = (uint16_t*)(p + 41943040);   // attn out (tokens x 1024) bf16
  float*    bias_t  = (float*)   (p + 50331648);   // 16 x 4096 f32, *log2e

  k_prep <<<dim3(5376), dim3(256), 0, stream>>>(x, x_bf, btab, bias_t,
                                                qkv_w, qkv_wt, proj_w, proj_wt);

  k_gemm  <<<dim3(24,64), dim3(256), 0, stream>>>(x_bf, qkv_wt, qkv_b, q_buf, k_buf, vt_buf);
  k_attn  <<<dim3(16,32), dim3(256), 0, stream>>>(q_buf, k_buf, vt_buf, bias_t, ao_buf);
  k_gemm2 <<<dim3(16,32), dim3(256), 0, stream>>>(ao_buf, proj_wt, proj_b, out);
}

// Round 18
// 117.998 us; speedup vs baseline: 1.0346x; 1.0346x over previous
//
#include <hip/hip_runtime.h>
#include <stdint.h>

// ---------- types & helpers ----------
typedef __attribute__((ext_vector_type(4))) float    f32x4;
typedef f32x4 __attribute__((aligned(4)))   f32x4u;  // 4B-aligned vector load (global allows it)
typedef __attribute__((ext_vector_type(8))) short    bf16x8;   // 8 bf16 (4 VGPRs) — MFMA operand
typedef __attribute__((ext_vector_type(2))) uint32_t u32x2;

#define MFMA16(a,b,c) __builtin_amdgcn_mfma_f32_16x16x32_bf16((a),(b),(c),0,0,0)

__device__ __forceinline__ uint16_t f2bf(float f){
  uint32_t u = __float_as_uint(f);
  return (uint16_t)((u + 0x7FFFu + ((u >> 16) & 1u)) >> 16);   // RNE
}

// packed f32x2 -> bf16x2 (RNE), single instruction
__device__ __forceinline__ uint32_t pk_bf16(float lo, float hi){
  uint32_t r; asm("v_cvt_pk_bf16_f32 %0, %1, %2" : "=v"(r) : "v"(lo), "v"(hi)); return r;
}

__device__ __forceinline__ float fast_exp2(float x){
  float r; asm("v_exp_f32 %0, %1" : "=v"(r) : "v"(x)); return r;
}

// async global->LDS, 16B per lane; LDS dest must be (wave-uniform base + lane*16)
__device__ __forceinline__ void gload16(const uint16_t* g, uint16_t* l){
  __builtin_amdgcn_global_load_lds((const __attribute__((address_space(1))) uint32_t*)g,
                                   (__attribute__((address_space(3))) uint32_t*)l, 16, 0, 0);
}

// ---------- fused prep (single launch, 5376 blocks) ----------
// blocks [0,4096):   x fp32 -> bf16
// blocks [4096,4352): bias_table transpose (16 x 4096, *log2e)
// blocks [4352,5120): qkv_w transpose-convert (1024x3072 -> 3072x1024 bf16)
// blocks [5120,5376): proj_w transpose-convert (1024x1024 -> 1024x1024 bf16)
__global__ void k_prep(const float* __restrict__ x, uint16_t* __restrict__ x_bf,
                       const float* __restrict__ btab, float* __restrict__ bias_t,
                       const float* __restrict__ qkv_w, uint16_t* __restrict__ qkv_wt,
                       const float* __restrict__ proj_w, uint16_t* __restrict__ proj_wt){
  __shared__ float tile[64][65];
  const int bx = blockIdx.x;
  if (bx < 4096){
    const size_t i = (size_t)(bx*256 + threadIdx.x) * 4;
    const f32x4 v = *(const f32x4*)(x + i);
    u32x2 pk = {pk_bf16(v[0], v[1]), pk_bf16(v[2], v[3])};
    *(u32x2*)(x_bf + i) = pk;
    return;
  }
  if (bx < 4352){
    const int i = (bx - 4096)*256 + threadIdx.x;
    if (i < 4095*16) bias_t[(i & 15)*4096 + (i >> 4)] = btab[i] * 1.4426950408889634f;
    return;
  }
  const float* in;  uint16_t* out;  int K, N, n0, k0;
  if (bx < 5120){
    const int b2 = bx - 4352;                        // 768 = 48 x 16
    in = qkv_w; out = qkv_wt; K = 1024; N = 3072;
    n0 = (b2 % 48)*64; k0 = (b2 / 48)*64;
  } else {
    const int b3 = bx - 5120;                        // 256 = 16 x 16
    in = proj_w; out = proj_wt; K = 1024; N = 1024;
    n0 = (b3 % 16)*64; k0 = (b3 / 16)*64;
  }
  const int tc = threadIdx.x & 63, tr = threadIdx.x >> 6;
  #pragma unroll
  for (int p=0;p<16;p++){ int r = p*4 + tr; tile[r][tc] = in[(size_t)(k0+r)*N + n0 + tc]; }
  __syncthreads();
  #pragma unroll
  for (int p=0;p<16;p++){ int r = p*4 + tr; out[(size_t)(n0+r)*K + k0 + tc] = f2bf(tile[tc][r]); }
}

// ---------- GEMM0: C(4096 x 3072) = A * Bt^T, BM=64, BN=128, BK=64; q/k/v scatter ----------
__global__ __launch_bounds__(256, 2) void k_gemm(
    const uint16_t* __restrict__ A, const uint16_t* __restrict__ Bt,
    const float* __restrict__ bias,
    uint16_t* __restrict__ qo, uint16_t* __restrict__ ko, uint16_t* __restrict__ vto)
{
  __shared__ __align__(16) uint16_t at[64*64];    // 8KB, [row 128B = 8 chunks], chunk ^= row&7
  __shared__ __align__(16) uint16_t bt[128*64];   // 16KB
  const int tid = threadIdx.x;
  const int lane = tid & 63, wc = tid >> 6;       // 4 column-waves
  const int g = lane >> 4, li = lane & 15;
  const int m0 = blockIdx.y * 64, n0 = blockIdx.x * 128;

  f32x4 acc[4][2] = {};

  const int srow = tid >> 3;                       // 0..31
  const int scg  = (tid & 7) ^ (srow & 7);

  for (int kt_ = 0; kt_ < 16; kt_++){
    const int kk = kt_*64;
    __syncthreads();
    #pragma unroll
    for (int j = 0; j < 2; j++)
      gload16(A  + (size_t)(m0 + j*32 + srow)*1024 + kk + scg*8, at + (j*256+tid)*8);
    #pragma unroll
    for (int j = 0; j < 4; j++)
      gload16(Bt + (size_t)(n0 + j*32 + srow)*1024 + kk + scg*8, bt + (j*256+tid)*8);
    asm volatile("s_waitcnt vmcnt(0)" ::: "memory");
    __syncthreads();

    bf16x8 af[2][4], bfr[2][2];
    #pragma unroll
    for (int mi=0; mi<4; mi++){
      int row = mi*16 + li, sw = row & 7;
      af[0][mi] = *(const bf16x8*)(at + row*64 + ((g     ^ sw)*8));
      af[1][mi] = *(const bf16x8*)(at + row*64 + (((4+g) ^ sw)*8));
    }
    #pragma unroll
    for (int ni=0; ni<2; ni++){
      int row = wc*32 + ni*16 + li, sw = row & 7;
      bfr[0][ni] = *(const bf16x8*)(bt + row*64 + ((g     ^ sw)*8));
      bfr[1][ni] = *(const bf16x8*)(bt + row*64 + (((4+g) ^ sw)*8));
    }
    #pragma unroll
    for (int s=0; s<2; s++)
      #pragma unroll
      for (int mi=0; mi<4; mi++)
        #pragma unroll
        for (int ni=0; ni<2; ni++)
          acc[mi][ni] = MFMA16(af[s][mi], bfr[s][ni], acc[mi][ni]);
  }

  #pragma unroll
  for (int ni=0; ni<2; ni++){
    const int c = n0 + wc*32 + ni*16 + li;
    const float bv = bias[c];
    const int which = c >> 10, cc = c & 1023;
    const int h = cc >> 6, d = cc & 63;
    #pragma unroll
    for (int mi=0; mi<4; mi++){
      const int trow = m0 + mi*16 + g*4;
      const int b_ = trow >> 11, lcl = trow & 2047;
      const f32x4 v4 = acc[mi][ni];
      if (which == 0){
        uint16_t* dst = qo + (((size_t)(b_*16 + h)*2048 + lcl)*64 + d);
        #pragma unroll
        for (int r=0;r<4;r++) dst[(size_t)r*64] = f2bf((v4[r] + bv) * 0.18033688011112042f);
      } else if (which == 1){
        uint16_t* dst = ko + (((size_t)(b_*16 + h)*2048 + lcl)*64 + d);
        #pragma unroll
        for (int r=0;r<4;r++) dst[(size_t)r*64] = f2bf(v4[r] + bv);
      } else {
        u32x2 pk = {pk_bf16(v4[0]+bv, v4[1]+bv), pk_bf16(v4[2]+bv, v4[3]+bv)};
        *(u32x2*)(vto + (((size_t)(b_*16 + h)*64 + d)*2048 + lcl)) = pk;
      }
    }
  }
}

// ---------- GEMM1 (proj): C(4096 x 1024) = A * Bt^T, BM=128, BN=64 -> 512 blocks ----------
__global__ __launch_bounds__(256, 2) void k_gemm2(
    const uint16_t* __restrict__ A, const uint16_t* __restrict__ Bt,
    const float* __restrict__ bias, float* __restrict__ outf)
{
  __shared__ __align__(16) uint16_t at[128*64];   // 16KB
  __shared__ __align__(16) uint16_t bt[64*64];    // 8KB
  const int tid = threadIdx.x;
  const int lane = tid & 63, w = tid >> 6;
  const int g = lane >> 4, li = lane & 15;
  const int wr = w >> 1, wc = w & 1;
  const int m0 = blockIdx.y * 128, n0 = blockIdx.x * 64;

  f32x4 acc[4][2] = {};
  const int srow = tid >> 3;
  const int scg  = (tid & 7) ^ (srow & 7);

  for (int kt_ = 0; kt_ < 16; kt_++){
    const int kk = kt_*64;
    __syncthreads();
    #pragma unroll
    for (int j = 0; j < 4; j++)
      gload16(A  + (size_t)(m0 + j*32 + srow)*1024 + kk + scg*8, at + (j*256+tid)*8);
    #pragma unroll
    for (int j = 0; j < 2; j++)
      gload16(Bt + (size_t)(n0 + j*32 + srow)*1024 + kk + scg*8, bt + (j*256+tid)*8);
    asm volatile("s_waitcnt vmcnt(0)" ::: "memory");
    __syncthreads();

    bf16x8 af[2][4], bfr[2][2];
    #pragma unroll
    for (int mi=0; mi<4; mi++){
      int row = wr*64 + mi*16 + li, sw = row & 7;
      af[0][mi] = *(const bf16x8*)(at + row*64 + ((g     ^ sw)*8));
      af[1][mi] = *(const bf16x8*)(at + row*64 + (((4+g) ^ sw)*8));
    }
    #pragma unroll
    for (int ni=0; ni<2; ni++){
      int row = wc*32 + ni*16 + li, sw = row & 7;
      bfr[0][ni] = *(const bf16x8*)(bt + row*64 + ((g     ^ sw)*8));
      bfr[1][ni] = *(const bf16x8*)(bt + row*64 + (((4+g) ^ sw)*8));
    }
    #pragma unroll
    for (int s=0; s<2; s++)
      #pragma unroll
      for (int mi=0; mi<4; mi++)
        #pragma unroll
        for (int ni=0; ni<2; ni++)
          acc[mi][ni] = MFMA16(af[s][mi], bfr[s][ni], acc[mi][ni]);
  }

  #pragma unroll
  for (int ni=0; ni<2; ni++){
    const int c = n0 + wc*32 + ni*16 + li;
    const float bv = bias[c];
    #pragma unroll
    for (int mi=0; mi<4; mi++){
      const int trow = m0 + wr*64 + mi*16 + g*4;
      float* dst = outf + (size_t)trow*1024 + c;
      const f32x4 v4 = acc[mi][ni];
      #pragma unroll
      for (int r=0;r<4;r++) dst[(size_t)r*1024] = v4[r] + bv;
    }
  }
}

// ---------- flash attention: 4 waves x 32 q (QBLK=128), KVBLK=64 (r15-verified best) ----------
// 16x16 MFMA structure: S^T = K*Q^T (K-frags shared across 2 q col-blocks), per-wave
// P LDS slab (reused across c), ones-MFMA rowsum, shuffle-free defer-max common path,
// 5-window diagonal bias with vmcnt(9/5) queue discipline, setprio on MFMA clusters.
// r16/r17 measured the 32x32 variant: correctness-fixed it is SLOWER (69 vs 63us;
// bank conflicts 2x, shfl_xor(32) on the chain). This 16x16 form is the local optimum.
// NOTE: launch_bounds stays (256,2) — (256,4) spills catastrophically (r8).
__device__ __forceinline__ void attn_tile(
    int t, bool last, int tid, int g, int li, int srow, int scg,
    const uint16_t* kbase, const uint16_t* vbase, const float* bb,
    const uint16_t* ktc, uint16_t* ktn, const uint16_t* vtc, uint16_t* vtn, uint16_t* pl,
    const bf16x8 (&qf)[2][2], bf16x8 ones,
    f32x4 (&o)[4][2], f32x4 (&o4)[2], float& mrun0, float& mrun1)
{
  const int kv0 = t*64;

  // bias for THIS tile: 5 diagonal windows; bv[c=0][mf]=bv5[mf+1], bv[c=1][mf]=bv5[mf]
  f32x4 bv5[5];
  #pragma unroll
  for (int j=0;j<5;j++)
    bv5[j] = *(const f32x4u*)(bb + kv0 + (j-1)*16 + g*4 - li);
  asm volatile("" ::: "memory");                           // pin issue order: bias -> staging

  if (!last){
    const int kv1 = kv0 + 64;
    gload16(kbase + (size_t)(kv1+srow)*64 + scg*8,         ktn + tid*8);
    gload16(kbase + (size_t)(kv1+srow+32)*64 + scg*8,      ktn + 2048 + tid*8);
    gload16(vbase + (size_t)srow*2048 + kv1 + scg*8,       vtn + tid*8);
    gload16(vbase + (size_t)(srow+32)*2048 + kv1 + scg*8,  vtn + 2048 + tid*8);
    // queue (old->new): stage(t)4, bias(t)5, stage(t+1)4 = 13 outstanding
    asm volatile("s_waitcnt vmcnt(9)" ::: "memory");       // retire stage(t); keep bias+stage(t+1)
  } else {
    asm volatile("s_waitcnt vmcnt(5)" ::: "memory");       // retire stage(t); keep bias(t)
  }
  __builtin_amdgcn_s_barrier();                            // A: tile t ready

  // S^T(64kv x 32q) = K * Q^T   (K-frags shared across both q col-blocks)
  f32x4 sa[4][2];
  __builtin_amdgcn_s_setprio(1);
  #pragma unroll
  for (int mf=0; mf<4; mf++){
    const int row = mf*16 + li, sw = row & 7;
    bf16x8 a0 = *(const bf16x8*)(ktc + row*64 + ((g     ^ sw)*8));
    bf16x8 a1 = *(const bf16x8*)(ktc + row*64 + (((4+g) ^ sw)*8));
    #pragma unroll
    for (int c=0;c<2;c++){
      f32x4 cfr = {};
      cfr = MFMA16(a0, qf[c][0], cfr);
      cfr = MFMA16(a1, qf[c][1], cfr);
      sa[mf][c] = cfr;
    }
  }
  __builtin_amdgcn_s_setprio(0);

  // bias add + lane-local max (q = c*16+li; kv = mf*16+g*4+r)
  float t0 = -__builtin_inff(), t1 = -__builtin_inff();
  #pragma unroll
  for (int mf=0; mf<4; mf++){
    sa[mf][0] += bv5[mf+1];
    sa[mf][1] += bv5[mf];
    #pragma unroll
    for (int r=0; r<4; r++){
      t0 = fmaxf(t0, sa[mf][0][r]);
      t1 = fmaxf(t1, sa[mf][1][r]);
    }
  }

  // defer-max (T13): common path has NO cross-lane ops; rare path full reduce.
  const int ok = (t0 <= mrun0 + 8.f) && (t1 <= mrun1 + 8.f);
  if (!__all(ok)){
    float r0 = t0, r1 = t1;
    r0 = fmaxf(r0, __shfl_xor(r0, 16)); r0 = fmaxf(r0, __shfl_xor(r0, 32));
    r1 = fmaxf(r1, __shfl_xor(r1, 16)); r1 = fmaxf(r1, __shfl_xor(r1, 32));
    const float mn0 = fmaxf(mrun0, r0), mn1 = fmaxf(mrun1, r1);
    const float a0 = fast_exp2(mrun0 - mn0), a1 = fast_exp2(mrun1 - mn1);
    #pragma unroll
    for (int mf=0; mf<4; mf++){ o[mf][0] *= a0; o[mf][1] *= a1; }
    o4[0] *= a0; o4[1] *= a1;
    mrun0 = mn0; mrun1 = mn1;
  }

  // V fragments (shared by both c-blocks)
  bf16x8 av[2][4];
  #pragma unroll
  for (int s=0; s<2; s++)
    #pragma unroll
    for (int mf=0; mf<4; mf++){
      const int row = mf*16 + li, sw = row & 7;
      av[s][mf] = *(const bf16x8*)(vtc + row*64 + (((4*s+g) ^ sw)*8));
    }

  // per c-block: P = exp2(S-m) -> bf16 -> P-slab (REUSED across c: 2KB/wave) -> PV
  const int swp2 = 2*(li & 7);
  #pragma unroll
  for (int c=0;c<2;c++){
    const float mr = c ? mrun1 : mrun0;
    #pragma unroll
    for (int mf=0; mf<4; mf++){
      float p0 = fast_exp2(sa[mf][c][0] - mr);
      float p1 = fast_exp2(sa[mf][c][1] - mr);
      float p2 = fast_exp2(sa[mf][c][2] - mr);
      float p3 = fast_exp2(sa[mf][c][3] - mr);
      u32x2 pk = {pk_bf16(p0,p1), pk_bf16(p2,p3)};
      *(u32x2*)(pl + li*64 + (((4*mf+g) ^ swp2)*4)) = pk;
    }
    __builtin_amdgcn_s_setprio(1);
    #pragma unroll
    for (int s=0; s<2; s++){
      bf16x8 pb = *(const bf16x8*)(pl + li*64 + (((8*s+2*g) ^ swp2)*4));
      o4[c] = MFMA16(ones, pb, o4[c]);
      #pragma unroll
      for (int mf=0; mf<4; mf++)
        o[mf][c] = MFMA16(av[s][mf], pb, o[mf][c]);
    }
    __builtin_amdgcn_s_setprio(0);
  }
  __builtin_amdgcn_s_barrier();                            // B: done reading tile t
}

__global__ __launch_bounds__(256, 2) void k_attn(
    const uint16_t* __restrict__ qg, const uint16_t* __restrict__ kg,
    const uint16_t* __restrict__ vg, const float* __restrict__ biast,
    uint16_t* __restrict__ outp)
{
  __shared__ __align__(16) uint16_t kt[2][64*64];  // K tile [kv][d], 16B-chunk ^= row&7 (16KB)
  __shared__ __align__(16) uint16_t vt[2][64*64];  // V^T tile [d][kv], same swizzle   (16KB)
  __shared__ __align__(16) uint16_t pt[4][16*64];  // per-wave P^T [16q][64kv], reused  (8KB)
  const int tid = threadIdx.x;
  const int lane = tid & 63, w = tid >> 6;         // 4 waves
  const int g = lane >> 4, li = lane & 15;
  const int bh = blockIdx.y, h = bh & 15, b_ = bh >> 4;
  const int qw = blockIdx.x*128 + w*32;            // wave's q base (32 rows)

  bf16x8 qf[2][2];
  #pragma unroll
  for (int c=0;c<2;c++){
    const uint16_t* qp = qg + ((size_t)bh*2048 + qw + c*16 + li)*64 + g*8;
    qf[c][0] = *(const bf16x8*)(qp);
    qf[c][1] = *(const bf16x8*)(qp + 32);
  }
  bf16x8 ones = (bf16x8)(short)0;                  // A-frag: row 0 = 1.0, rows 1-15 = 0
  if (li == 0){ const short v = (short)0x3F80; ones = (bf16x8){v,v,v,v,v,v,v,v}; }

  f32x4 o[4][2] = {};
  f32x4 o4[2] = {};
  float mrun0 = -__builtin_inff(), mrun1 = -__builtin_inff();

  const uint16_t* kbase = kg + (size_t)bh*(2048*64);
  const uint16_t* vbase = vg + (size_t)bh*(64*2048);
  const int srow = tid >> 3;                       // 0..31
  const int scg  = (tid & 7) ^ (srow & 7);
  const float* bb = biast + h*4096 + 2047 - qw;    // + kv - (c*16+li)
  uint16_t* pl = &pt[w][0];

  // prologue: stage tile 0
  gload16(kbase + (size_t)srow*64 + scg*8,         &kt[0][tid*8]);
  gload16(kbase + (size_t)(srow+32)*64 + scg*8,    &kt[0][2048 + tid*8]);
  gload16(vbase + (size_t)srow*2048 + scg*8,       &vt[0][tid*8]);
  gload16(vbase + (size_t)(srow+32)*2048 + scg*8,  &vt[0][2048 + tid*8]);

  for (int tt = 0; tt < 32; tt += 2){
    attn_tile(tt,   false,    tid, g, li, srow, scg, kbase, vbase, bb,
              &kt[0][0], &kt[1][0], &vt[0][0], &vt[1][0], pl,
              qf, ones, o, o4, mrun0, mrun1);
    attn_tile(tt+1, tt == 30, tid, g, li, srow, scg, kbase, vbase, bb,
              &kt[1][0], &kt[0][0], &vt[1][0], &vt[0][0], pl,
              qf, ones, o, o4, mrun0, mrun1);
  }

  // row sums in o4[c] reg 0 of g=0 lanes; broadcast; write normalized O
  const float ls0 = __shfl(o4[0][0], li);
  const float ls1 = __shfl(o4[1][0], li);
  const float inv0 = 1.0f / ls0, inv1 = 1.0f / ls1;
  #pragma unroll
  for (int c=0;c<2;c++){
    const float inv = c ? inv1 : inv0;
    const size_t token = (size_t)b_*2048 + qw + c*16 + li;
    #pragma unroll
    for (int mf=0; mf<4; mf++){
      u32x2 pk = {pk_bf16(o[mf][c][0]*inv, o[mf][c][1]*inv),
                  pk_bf16(o[mf][c][2]*inv, o[mf][c][3]*inv)};
      *(u32x2*)(outp + token*1024 + h*64 + mf*16 + g*4) = pk;
    }
  }
}

// ---------- launch ----------
extern "C" void kernel_launch(void* const* d_in, const int* in_sizes, int n_in,
                              void* d_out, int out_size, void* d_ws, size_t ws_size,
                              hipStream_t stream)
{
  const float* x      = (const float*)d_in[0];
  const float* qkv_w  = (const float*)d_in[1];
  const float* qkv_b  = (const float*)d_in[2];
  const float* proj_w = (const float*)d_in[3];
  const float* proj_b = (const float*)d_in[4];
  const float* btab   = (const float*)d_in[5];
  float* out = (float*)d_out;

  char* p = (char*)d_ws;
  uint16_t* x_bf    = (uint16_t*)(p);
  uint16_t* qkv_wt  = (uint16_t*)(p + 8388608);
  uint16_t* proj_wt = (uint16_t*)(p + 14680064);
  uint16_t* q_buf   = (uint16_t*)(p + 16777216);   // (b,h,l,d) bf16, prescaled
  uint16_t* k_buf   = (uint16_t*)(p + 25165824);   // (b,h,l,d) bf16
  uint16_t* vt_buf  = (uint16_t*)(p + 33554432);   // (b,h,d,l) bf16
  uint16_t* ao_buf  = (uint16_t*)(p + 41943040);   // attn out (tokens x 1024) bf16
  float*    bias_t  = (float*)   (p + 50331648);   // 16 x 4096 f32, *log2e

  k_prep <<<dim3(5376), dim3(256), 0, stream>>>(x, x_bf, btab, bias_t,
                                                qkv_w, qkv_wt, proj_w, proj_wt);

  k_gemm  <<<dim3(24,64), dim3(256), 0, stream>>>(x_bf, qkv_wt, qkv_b, q_buf, k_buf, vt_buf);
  k_attn  <<<dim3(16,32), dim3(256), 0, stream>>>(q_buf, k_buf, vt_buf, bias_t, ao_buf);
  k_gemm2 <<<dim3(16,32), dim3(256), 0, stream>>>(ao_buf, proj_wt, proj_b, out);
}